// Round 9
// baseline (294.862 us; speedup 1.0000x reference)
//
#include <hip/hip_runtime.h>
#include <hip/hip_bf16.h>

typedef __attribute__((ext_vector_type(4))) float f32x4;
typedef __attribute__((ext_vector_type(8))) __bf16 bf16x8;
typedef __attribute__((ext_vector_type(4))) __bf16 bf16x4;
typedef __attribute__((ext_vector_type(4))) unsigned int u32x4;
typedef unsigned long long u64;
typedef unsigned int u32;

#define DIMQ 512
#define NSEQ 4096
#define NHEAD 16
#define HDIM 32
#define SCALE_QK 0.17677669529663687f
#define C2F (SCALE_QK * 1.4426950408889634f)  // scale * log2(e), folded into Q

__device__ __forceinline__ void gload16(void* lds, const void* g) {
  __builtin_amdgcn_global_load_lds(
      (const __attribute__((address_space(1))) void*)g,
      (__attribute__((address_space(3))) void*)lds, 16, 0, 0);
}

// ---------------- conversion kernels ----------------

__global__ __launch_bounds__(256) void k_cvt_bf16(const float* __restrict__ in,
                                                  __bf16* __restrict__ out) {
  int i = blockIdx.x * 256 + threadIdx.x;
  float4 v = reinterpret_cast<const float4*>(in)[i];
  bf16x4 o;
  o.x = (__bf16)v.x; o.y = (__bf16)v.y; o.z = (__bf16)v.z; o.w = (__bf16)v.w;
  reinterpret_cast<bf16x4*>(out)[i] = o;
}

// in: fp32 [512][Nc]  ->  out: bf16 [Nc][512]  (transpose via LDS tile)
__global__ __launch_bounds__(256) void k_cvtT(const float* __restrict__ in,
                                              __bf16* __restrict__ out, int Nc) {
  __shared__ __bf16 t[64][72];
  int k0 = blockIdx.y * 64, n0 = blockIdx.x * 64;
  int c = threadIdx.x & 63, rr = threadIdx.x >> 6;
#pragma unroll
  for (int i = 0; i < 16; ++i) {
    int r = rr * 16 + i;
    t[r][c] = (__bf16)in[(size_t)(k0 + r) * Nc + n0 + c];
  }
  __syncthreads();
#pragma unroll
  for (int i = 0; i < 16; ++i) {
    int r = rr * 16 + i;
    out[(size_t)(n0 + r) * 512 + k0 + c] = t[c][r];
  }
}

// int32 mask [4096][4096] -> PERMUTED bit mask [4096][64] u64.
// Lane l ballots column kvp(l) so that, in the attention kernel, the two mask
// bits of each packed-bf16 pair (pa elements 2w,2w+1) sit 16 bits apart:
//   mt bit l  <->  kv = 32*l5 | 16*l1 | (l3:2)*4 | 2*l0 | l4
__global__ __launch_bounds__(256) void k_maskbits(const int* __restrict__ mask,
                                                  u64* __restrict__ bits) {
  int row = blockIdx.x;
  int l = threadIdx.x & 63, w = threadIdx.x >> 6;
  const int jj = l >> 5, odd = (l >> 4) & 1, gg = (l >> 2) & 3, wb = l & 3;
  const int kvp = 32 * jj + 16 * (wb >> 1) + 4 * gg + 2 * (wb & 1) + odd;
  const int* mr = mask + (size_t)row * NSEQ;
  for (int t = w; t < 64; t += 4) {
    u64 b = __ballot(mr[t * 64 + kvp] != 0);
    if (l == 0) bits[(size_t)row * 64 + t] = b;
  }
}

// ---------------- shared GEMM main loop (m97-style, swizzled gload_lds) ----------------
__device__ __forceinline__ void gemm_mainloop(const __bf16* __restrict__ A,
                                              const __bf16* __restrict__ Bt,
                                              int m0, int n0,
                                              __bf16* As, __bf16* Bs,
                                              f32x4 acc[4][4]) {
  const int tid = threadIdx.x, l = tid & 63, w = tid >> 6;
  const int wr = w >> 1, wc = w & 1;
  for (int kt = 0; kt < DIMQ; kt += 64) {
    __syncthreads();
#pragma unroll
    for (int it = 0; it < 4; ++it) {
      int c = it * 256 + tid;
      int row = c >> 3, j = c & 7, js = j ^ (row & 7);
      gload16(As + (size_t)(it * 256 + w * 64) * 8,
              A + (size_t)(m0 + row) * DIMQ + kt + js * 8);
      gload16(Bs + (size_t)(it * 256 + w * 64) * 8,
              Bt + (size_t)(n0 + row) * DIMQ + kt + js * 8);
    }
    __syncthreads();
#pragma unroll
    for (int kk = 0; kk < 2; ++kk) {
      bf16x8 a[4], b[4];
#pragma unroll
      for (int mt = 0; mt < 4; ++mt) {
        int row = wr * 64 + mt * 16 + (l & 15);
        int g = (kk * 4 + (l >> 4)) ^ (row & 7);
        a[mt] = *reinterpret_cast<const bf16x8*>((const char*)As + row * 128 + g * 16);
      }
#pragma unroll
      for (int nt = 0; nt < 4; ++nt) {
        int row = wc * 64 + nt * 16 + (l & 15);
        int g = (kk * 4 + (l >> 4)) ^ (row & 7);
        b[nt] = *reinterpret_cast<const bf16x8*>((const char*)Bs + row * 128 + g * 16);
      }
#pragma unroll
      for (int mt = 0; mt < 4; ++mt)
#pragma unroll
        for (int nt = 0; nt < 4; ++nt)
          acc[mt][nt] = __builtin_amdgcn_mfma_f32_16x16x32_bf16(a[mt], b[nt], acc[mt][nt], 0, 0, 0);
    }
  }
}

// ---------------- QKV GEMM (epilogue: head layout; Q pre-scaled; V transposed + k-permuted) ----------------
__global__ __launch_bounds__(256) void k_gemm_qkv(const __bf16* __restrict__ A,
                                                  const __bf16* __restrict__ Bt,
                                                  __bf16* __restrict__ Qh,
                                                  __bf16* __restrict__ Kh,
                                                  __bf16* __restrict__ VT) {
  __shared__ __bf16 As[128 * 64], Bs[128 * 64];
  f32x4 acc[4][4] = {};
  const int l = threadIdx.x & 63, w = threadIdx.x >> 6, wr = w >> 1, wc = w & 1;
  const int m0 = blockIdx.y * 128, n0 = blockIdx.x * 128;
  gemm_mainloop(A, Bt, m0, n0, As, Bs, acc);
#pragma unroll
  for (int nt = 0; nt < 4; ++nt) {
    int n = n0 + wc * 64 + nt * 16 + (l & 15);
    int sec = n >> 9;           // 0=q 1=k 2=v
    int hh = (n >> 5) & 15;     // head
    int d = n & 31;             // dim in head
#pragma unroll
    for (int mt = 0; mt < 4; ++mt) {
      int m = m0 + wr * 64 + mt * 16 + (l >> 4) * 4;
      int bb = m >> 12, nn = m & 4095;
      size_t bh = (size_t)bb * NHEAD + hh;
      f32x4 v = acc[mt][nt];
      if (sec == 0) {
        __bf16* p = Qh + (bh * NSEQ + nn) * HDIM + d;
        p[0] = (__bf16)(v[0] * C2F); p[HDIM] = (__bf16)(v[1] * C2F);
        p[2 * HDIM] = (__bf16)(v[2] * C2F); p[3 * HDIM] = (__bf16)(v[3] * C2F);
      } else if (sec == 1) {
        __bf16* p = Kh + (bh * NSEQ + nn) * HDIM + d;
        p[0] = (__bf16)v[0]; p[HDIM] = (__bf16)v[1];
        p[2 * HDIM] = (__bf16)v[2]; p[3 * HDIM] = (__bf16)v[3];
      } else {
        // k-permuted V: within each 32-kv group, low5 = hi*16 + g*4 + r -> g*8 + hi*4 + r
        // (nn % 4 == 0, so r = 0 for the vector base)
        int low = nn & 31;
        int nnp = (nn & ~31) | (((low >> 2) & 3) << 3) | (((low >> 4) & 1) << 2);
        bf16x4 o;
        o.x = (__bf16)v[0]; o.y = (__bf16)v[1]; o.z = (__bf16)v[2]; o.w = (__bf16)v[3];
        *reinterpret_cast<bf16x4*>(VT + (bh * HDIM + d) * NSEQ + nnp) = o;
      }
    }
  }
}

// ---------------- fused masked attention, v6 ----------------
// As v5 (grid 2048 XCD-decoded, 4 waves x 16 q-rows, LDS double-buffered K/V,
// swapped QK^T, no-max exp2, k-permuted V, MFMA row-sums), but masking is now
// applied to PACKED bf16 p-values with the ballot-permuted bitmask:
//   per u32 pair: z = (x>>w) & 0x10001; pw &= (z<<16)-z   (all full-rate VALU)
__device__ __forceinline__ void attn_compute(const __bf16* __restrict__ Kl,
                                             const __bf16* __restrict__ Vl,
                                             bf16x8 qf, u64 mw,
                                             f32x4 acc[2], f32x4& accS,
                                             int kOff, const int vOff[2][2],
                                             bf16x8 ones, int g) {
  bf16x8 kf[4];
#pragma unroll
  for (int f = 0; f < 4; ++f)
    kf[f] = *reinterpret_cast<const bf16x8*>(Kl + kOff + f * 512);

  bf16x8 vvb[2][2];  // [jj][dt], single b128 each
#pragma unroll
  for (int jj = 0; jj < 2; ++jj)
#pragma unroll
    for (int dt = 0; dt < 2; ++dt)
      vvb[jj][dt] = *reinterpret_cast<const bf16x8*>(Vl + vOff[jj][dt]);

  const f32x4 z4 = {0.f, 0.f, 0.f, 0.f};
  f32x4 s[4];
#pragma unroll
  for (int f = 0; f < 4; ++f)  // S^T: lane holds q=q16, k=16f+4g+r
    s[f] = __builtin_amdgcn_mfma_f32_16x16x32_bf16(kf[f], qf, z4, 0, 0, 0);

  float p[4][4];
#pragma unroll
  for (int f = 0; f < 4; ++f)
#pragma unroll
    for (int r = 0; r < 4; ++r) p[f][r] = __builtin_exp2f(s[f][r]);

  const u32 x0 = ((u32)mw) >> (g * 4);
  const u32 x1 = ((u32)(mw >> 32)) >> (g * 4);

#pragma unroll
  for (int jj = 0; jj < 2; ++jj) {
    const u32 x = jj ? x1 : x0;
    bf16x8 pa;  // k order e = hi*4 + r matches permuted-V b128 order
#pragma unroll
    for (int r = 0; r < 4; ++r) {
      pa[r] = (__bf16)p[2 * jj][r];
      pa[r + 4] = (__bf16)p[2 * jj + 1][r];
    }
    u32x4 pw = __builtin_bit_cast(u32x4, pa);
#pragma unroll
    for (int wq = 0; wq < 4; ++wq) {
      u32 zb = (x >> wq) & 0x10001u;
      pw[wq] &= (zb << 16) - zb;  // 0 / 0xFFFF / 0xFFFF0000 / 0xFFFFFFFF
    }
    bf16x8 pm = __builtin_bit_cast(bf16x8, pw);
    accS = __builtin_amdgcn_mfma_f32_16x16x32_bf16(pm, ones, accS, 0, 0, 0);
#pragma unroll
    for (int dt = 0; dt < 2; ++dt)
      acc[dt] = __builtin_amdgcn_mfma_f32_16x16x32_bf16(pm, vvb[jj][dt], acc[dt], 0, 0, 0);
  }
}

__global__ __launch_bounds__(256, 8) void k_attn(const __bf16* __restrict__ Qh,
                                                 const __bf16* __restrict__ Kh,
                                                 const __bf16* __restrict__ VT,
                                                 const u64* __restrict__ mbits,
                                                 __bf16* __restrict__ O) {
  __shared__ __bf16 Klds[2][2048];  // [64 rows][4 slots x 16B], slot-swizzled
  __shared__ __bf16 Vlds[2][2048];  // [32 d][8 granules x 16B], granule-swizzled
  const int tid = threadIdx.x;
  const int l = tid & 63, w = tid >> 6;
  const int g = l >> 4, q16 = l & 15;
  const int bid = blockIdx.x;
  const int bh = (bid & 7) * 4 + ((bid >> 3) & 3);  // XCD-aware decode
  const int qx = bid >> 5;                          // 0..63
  const int q0 = qx * 64 + w * 16;
  const __bf16* Qb = Qh + (size_t)bh * NSEQ * HDIM;
  const __bf16* Kb = Kh + (size_t)bh * NSEQ * HDIM;
  const __bf16* Vb = VT + (size_t)bh * HDIM * NSEQ;  // [32 d][4096 kp]
  const u64* mr = mbits + (size_t)(q0 + q16) * 64;

  // staging sources (pre-swizzled: linear LDS dest + swizzled read match)
  const int rk = tid >> 2, gsK = (tid & 3) ^ ((rk >> 1) & 3);
  const __bf16* srcK = Kb + (size_t)rk * HDIM + gsK * 8;   // += t*2048
  const int dv = tid >> 3, gv = (tid & 7) ^ (dv & 7);
  const __bf16* srcV = Vb + (size_t)dv * NSEQ + gv * 8;    // += t*64

  // LDS read offsets (loop-invariant, elements)
  const int kOff = q16 * 32 + (g ^ ((q16 >> 1) & 3)) * 8;
  int vOff[2][2];
#pragma unroll
  for (int jj = 0; jj < 2; ++jj)
#pragma unroll
    for (int dt = 0; dt < 2; ++dt) {
      int d = dt * 16 + q16;
      vOff[jj][dt] = d * 64 + ((4 * jj + g) ^ (d & 7)) * 8;
    }

  bf16x8 qf = *reinterpret_cast<const bf16x8*>(
      Qb + (size_t)(q0 + q16) * HDIM + g * 8);

  bf16x8 ones;
#pragma unroll
  for (int e = 0; e < 8; ++e) ones[e] = (__bf16)1.0f;

  f32x4 acc[2] = {};
  f32x4 accS = {};

  // prologue: stage tile 0 into buf0
  gload16(&Klds[0][0] + tid * 8, srcK);
  gload16(&Vlds[0][0] + tid * 8, srcV);
  u64 a0 = mr[0], b0;
  __syncthreads();

  for (int t = 0; t < 64; t += 2) {
    // phase A: stage t+1 -> buf1, compute t from buf0
    gload16(&Klds[1][0] + tid * 8, srcK + (size_t)(t + 1) * 2048);
    gload16(&Vlds[1][0] + tid * 8, srcV + (size_t)(t + 1) * 64);
    b0 = mr[t + 1];
    attn_compute(&Klds[0][0], &Vlds[0][0], qf, a0, acc, accS, kOff, vOff, ones, g);
    __syncthreads();
    // phase B: stage t+2 -> buf0 (clamped), compute t+1 from buf1
    const int t2 = (t + 2 < 64) ? t + 2 : 63;
    gload16(&Klds[0][0] + tid * 8, srcK + (size_t)t2 * 2048);
    gload16(&Vlds[0][0] + tid * 8, srcV + (size_t)t2 * 64);
    a0 = mr[t2];
    attn_compute(&Klds[1][0], &Vlds[1][0], qf, b0, acc, accS, kOff, vOff, ones, g);
    __syncthreads();
  }

  const int bb = bh >> 4, hh = bh & 15;
#pragma unroll
  for (int r = 0; r < 4; ++r) {
    float inv = 1.f / accS[r];  // denominator in the same lane/reg as numerator
    int qrow = q0 + g * 4 + r;
#pragma unroll
    for (int dt = 0; dt < 2; ++dt)
      O[((size_t)bb * NSEQ + qrow) * DIMQ + hh * HDIM + dt * 16 + q16] =
          (__bf16)(acc[dt][r] * inv);
  }
}

// ---------------- output projection GEMM (fp32 output) ----------------
__global__ __launch_bounds__(256) void k_gemm_proj(const __bf16* __restrict__ A,
                                                   const __bf16* __restrict__ Bt,
                                                   float* __restrict__ Out) {
  __shared__ __bf16 As[128 * 64], Bs[128 * 64];
  f32x4 acc[4][4] = {};
  const int l = threadIdx.x & 63, w = threadIdx.x >> 6, wr = w >> 1, wc = w & 1;
  const int m0 = blockIdx.y * 128, n0 = blockIdx.x * 128;
  gemm_mainloop(A, Bt, m0, n0, As, Bs, acc);
#pragma unroll
  for (int nt = 0; nt < 4; ++nt) {
    int n = n0 + wc * 64 + nt * 16 + (l & 15);
#pragma unroll
    for (int mt = 0; mt < 4; ++mt) {
      int m = m0 + wr * 64 + mt * 16 + (l >> 4) * 4;
      f32x4 v = acc[mt][nt];
      float* p = Out + (size_t)m * DIMQ + n;
      p[0] = v[0]; p[DIMQ] = v[1];
      p[2 * DIMQ] = v[2]; p[3 * DIMQ] = v[3];
    }
  }
}

// ---------------- launcher ----------------
extern "C" void kernel_launch(void* const* d_in, const int* in_sizes, int n_in,
                              void* d_out, int out_size, void* d_ws, size_t ws_size,
                              hipStream_t stream) {
  (void)in_sizes; (void)n_in; (void)out_size; (void)ws_size;
  const float* batch  = (const float*)d_in[0];
  const float* w_qkv  = (const float*)d_in[1];
  const float* w_proj = (const float*)d_in[2];
  const int*   cmask  = (const int*)d_in[3];

  __bf16* Abf = (__bf16*)d_ws;                       // 8192*512 bf16
  __bf16* WqT = Abf + (size_t)8192 * 512;            // 1536*512
  __bf16* WpT = WqT + (size_t)1536 * 512;            // 512*512
  u64*    mb  = (u64*)(WpT + (size_t)512 * 512);     // 4096*64 u64
  __bf16* Qh  = (__bf16*)(mb + (size_t)4096 * 64);   // 32*4096*32
  __bf16* Kh  = Qh + (size_t)32 * NSEQ * HDIM;
  __bf16* VT  = Kh + (size_t)32 * NSEQ * HDIM;
  __bf16* Obf = VT + (size_t)32 * NSEQ * HDIM;       // 8192*512

  k_cvt_bf16<<<4096, 256, 0, stream>>>(batch, Abf);
  k_cvtT<<<dim3(24, 8), 256, 0, stream>>>(w_qkv, WqT, 1536);
  k_cvtT<<<dim3(8, 8), 256, 0, stream>>>(w_proj, WpT, 512);
  k_maskbits<<<4096, 256, 0, stream>>>(cmask, mb);
  k_gemm_qkv<<<dim3(12, 64), 256, 0, stream>>>(Abf, WqT, Qh, Kh, VT);
  k_attn<<<2048, 256, 0, stream>>>(Qh, Kh, VT, mb, Obf);
  k_gemm_proj<<<dim3(4, 64), 256, 0, stream>>>(Obf, WpT, (float*)d_out);
}

// Round 10
// 247.770 us; speedup vs baseline: 1.1901x; 1.1901x over previous
//
#include <hip/hip_runtime.h>
#include <hip/hip_bf16.h>

typedef __attribute__((ext_vector_type(4))) float f32x4;
typedef __attribute__((ext_vector_type(8))) __bf16 bf16x8;
typedef __attribute__((ext_vector_type(4))) __bf16 bf16x4;
typedef __attribute__((ext_vector_type(4))) unsigned int u32x4;
typedef unsigned long long u64;
typedef unsigned int u32;

#define DIMQ 512
#define NSEQ 4096
#define NHEAD 16
#define HDIM 32
#define SCALE_QK 0.17677669529663687f
#define C2F (SCALE_QK * 1.4426950408889634f)  // scale * log2(e), folded into Q

__device__ __forceinline__ void gload16(void* lds, const void* g) {
  __builtin_amdgcn_global_load_lds(
      (const __attribute__((address_space(1))) void*)g,
      (__attribute__((address_space(3))) void*)lds, 16, 0, 0);
}

// ---------------- conversion kernels ----------------

__global__ __launch_bounds__(256) void k_cvt_bf16(const float* __restrict__ in,
                                                  __bf16* __restrict__ out) {
  int i = blockIdx.x * 256 + threadIdx.x;
  float4 v = reinterpret_cast<const float4*>(in)[i];
  bf16x4 o;
  o.x = (__bf16)v.x; o.y = (__bf16)v.y; o.z = (__bf16)v.z; o.w = (__bf16)v.w;
  reinterpret_cast<bf16x4*>(out)[i] = o;
}

// in: fp32 [512][Nc]  ->  out: bf16 [Nc][512]  (transpose via LDS tile)
__global__ __launch_bounds__(256) void k_cvtT(const float* __restrict__ in,
                                              __bf16* __restrict__ out, int Nc) {
  __shared__ __bf16 t[64][72];
  int k0 = blockIdx.y * 64, n0 = blockIdx.x * 64;
  int c = threadIdx.x & 63, rr = threadIdx.x >> 6;
#pragma unroll
  for (int i = 0; i < 16; ++i) {
    int r = rr * 16 + i;
    t[r][c] = (__bf16)in[(size_t)(k0 + r) * Nc + n0 + c];
  }
  __syncthreads();
#pragma unroll
  for (int i = 0; i < 16; ++i) {
    int r = rr * 16 + i;
    out[(size_t)(n0 + r) * 512 + k0 + c] = t[c][r];
  }
}

// int32 mask [4096][4096] -> PERMUTED bit mask [4096][64] u64.
// Lane l ballots column kvp(l) so the two mask bits of each packed-bf16 pair
// (pa elements 2w,2w+1) sit 16 bits apart:
//   mt bit l  <->  kv = 32*l5 | 16*l1 | (l3:2)*4 | 2*l0 | l4
__global__ __launch_bounds__(256) void k_maskbits(const int* __restrict__ mask,
                                                  u64* __restrict__ bits) {
  int row = blockIdx.x;
  int l = threadIdx.x & 63, w = threadIdx.x >> 6;
  const int jj = l >> 5, odd = (l >> 4) & 1, gg = (l >> 2) & 3, wb = l & 3;
  const int kvp = 32 * jj + 16 * (wb >> 1) + 4 * gg + 2 * (wb & 1) + odd;
  const int* mr = mask + (size_t)row * NSEQ;
  for (int t = w; t < 64; t += 4) {
    u64 b = __ballot(mr[t * 64 + kvp] != 0);
    if (l == 0) bits[(size_t)row * 64 + t] = b;
  }
}

// ---------------- shared GEMM main loop (m97-style, swizzled gload_lds) ----------------
__device__ __forceinline__ void gemm_mainloop(const __bf16* __restrict__ A,
                                              const __bf16* __restrict__ Bt,
                                              int m0, int n0,
                                              __bf16* As, __bf16* Bs,
                                              f32x4 acc[4][4]) {
  const int tid = threadIdx.x, l = tid & 63, w = tid >> 6;
  const int wr = w >> 1, wc = w & 1;
  for (int kt = 0; kt < DIMQ; kt += 64) {
    __syncthreads();
#pragma unroll
    for (int it = 0; it < 4; ++it) {
      int c = it * 256 + tid;
      int row = c >> 3, j = c & 7, js = j ^ (row & 7);
      gload16(As + (size_t)(it * 256 + w * 64) * 8,
              A + (size_t)(m0 + row) * DIMQ + kt + js * 8);
      gload16(Bs + (size_t)(it * 256 + w * 64) * 8,
              Bt + (size_t)(n0 + row) * DIMQ + kt + js * 8);
    }
    __syncthreads();
#pragma unroll
    for (int kk = 0; kk < 2; ++kk) {
      bf16x8 a[4], b[4];
#pragma unroll
      for (int mt = 0; mt < 4; ++mt) {
        int row = wr * 64 + mt * 16 + (l & 15);
        int g = (kk * 4 + (l >> 4)) ^ (row & 7);
        a[mt] = *reinterpret_cast<const bf16x8*>((const char*)As + row * 128 + g * 16);
      }
#pragma unroll
      for (int nt = 0; nt < 4; ++nt) {
        int row = wc * 64 + nt * 16 + (l & 15);
        int g = (kk * 4 + (l >> 4)) ^ (row & 7);
        b[nt] = *reinterpret_cast<const bf16x8*>((const char*)Bs + row * 128 + g * 16);
      }
#pragma unroll
      for (int mt = 0; mt < 4; ++mt)
#pragma unroll
        for (int nt = 0; nt < 4; ++nt)
          acc[mt][nt] = __builtin_amdgcn_mfma_f32_16x16x32_bf16(a[mt], b[nt], acc[mt][nt], 0, 0, 0);
    }
  }
}

// ---------------- QKV GEMM (epilogue: head layout; Q pre-scaled; V transposed + k-permuted) ----------------
__global__ __launch_bounds__(256) void k_gemm_qkv(const __bf16* __restrict__ A,
                                                  const __bf16* __restrict__ Bt,
                                                  __bf16* __restrict__ Qh,
                                                  __bf16* __restrict__ Kh,
                                                  __bf16* __restrict__ VT) {
  __shared__ __bf16 As[128 * 64], Bs[128 * 64];
  f32x4 acc[4][4] = {};
  const int l = threadIdx.x & 63, w = threadIdx.x >> 6, wr = w >> 1, wc = w & 1;
  const int m0 = blockIdx.y * 128, n0 = blockIdx.x * 128;
  gemm_mainloop(A, Bt, m0, n0, As, Bs, acc);
#pragma unroll
  for (int nt = 0; nt < 4; ++nt) {
    int n = n0 + wc * 64 + nt * 16 + (l & 15);
    int sec = n >> 9;           // 0=q 1=k 2=v
    int hh = (n >> 5) & 15;     // head
    int d = n & 31;             // dim in head
#pragma unroll
    for (int mt = 0; mt < 4; ++mt) {
      int m = m0 + wr * 64 + mt * 16 + (l >> 4) * 4;
      int bb = m >> 12, nn = m & 4095;
      size_t bh = (size_t)bb * NHEAD + hh;
      f32x4 v = acc[mt][nt];
      if (sec == 0) {
        __bf16* p = Qh + (bh * NSEQ + nn) * HDIM + d;
        p[0] = (__bf16)(v[0] * C2F); p[HDIM] = (__bf16)(v[1] * C2F);
        p[2 * HDIM] = (__bf16)(v[2] * C2F); p[3 * HDIM] = (__bf16)(v[3] * C2F);
      } else if (sec == 1) {
        __bf16* p = Kh + (bh * NSEQ + nn) * HDIM + d;
        p[0] = (__bf16)v[0]; p[HDIM] = (__bf16)v[1];
        p[2 * HDIM] = (__bf16)v[2]; p[3 * HDIM] = (__bf16)v[3];
      } else {
        // k-permuted V: within each 32-kv group, low5 = hi*16 + g*4 + r -> g*8 + hi*4 + r
        // (nn % 4 == 0, so r = 0 for the vector base)
        int low = nn & 31;
        int nnp = (nn & ~31) | (((low >> 2) & 3) << 3) | (((low >> 4) & 1) << 2);
        bf16x4 o;
        o.x = (__bf16)v[0]; o.y = (__bf16)v[1]; o.z = (__bf16)v[2]; o.w = (__bf16)v[3];
        *reinterpret_cast<bf16x4*>(VT + (bh * HDIM + d) * NSEQ + nnp) = o;
      }
    }
  }
}

// ---------------- fused masked attention, v7 ----------------
// grid 1024 (XCD decode), 4 waves x 32 q-rows = 128 q-rows/block: K/V frags are
// rt-invariant so each wave's 8KB LDS read serves 2x the q-rows of v5/v6.
// Packed-AND masking with ballot-permuted bitmask, restructured per-(rt,jj) so
// lifetimes stay short (no spills). __launch_bounds__(256,4) -> 128 VGPR cap.
__device__ __forceinline__ void attn_compute(const __bf16* __restrict__ Kl,
                                             const __bf16* __restrict__ Vl,
                                             const bf16x8 qf[2], u64 mw0, u64 mw1,
                                             f32x4 acc[2][2], f32x4 accS[2],
                                             int kOff, const int vOff[2][2],
                                             bf16x8 ones, int g) {
  bf16x8 kf[4];
#pragma unroll
  for (int f = 0; f < 4; ++f)
    kf[f] = *reinterpret_cast<const bf16x8*>(Kl + kOff + f * 512);

  bf16x8 vvb[2][2];  // [jj][dt], single b128 each
#pragma unroll
  for (int jj = 0; jj < 2; ++jj)
#pragma unroll
    for (int dt = 0; dt < 2; ++dt)
      vvb[jj][dt] = *reinterpret_cast<const bf16x8*>(Vl + vOff[jj][dt]);

  const f32x4 z4 = {0.f, 0.f, 0.f, 0.f};
#pragma unroll
  for (int rt = 0; rt < 2; ++rt) {
    const u64 mw = rt ? mw1 : mw0;
#pragma unroll
    for (int jj = 0; jj < 2; ++jj) {
      // S^T for kv halves f=2jj, 2jj+1: lane holds q=q16, k=16f+4g+r
      f32x4 s0 = __builtin_amdgcn_mfma_f32_16x16x32_bf16(kf[2 * jj], qf[rt], z4, 0, 0, 0);
      f32x4 s1 = __builtin_amdgcn_mfma_f32_16x16x32_bf16(kf[2 * jj + 1], qf[rt], z4, 0, 0, 0);
      bf16x8 pa;  // k order e = hi*4 + r matches permuted-V b128 order
#pragma unroll
      for (int r = 0; r < 4; ++r) {
        pa[r] = (__bf16)__builtin_exp2f(s0[r]);
        pa[r + 4] = (__bf16)__builtin_exp2f(s1[r]);
      }
      const u32 x = ((u32)(mw >> (32 * jj))) >> (g * 4);
      u32x4 pw = __builtin_bit_cast(u32x4, pa);
#pragma unroll
      for (int wq = 0; wq < 4; ++wq) {
        u32 zb = (x >> wq) & 0x10001u;
        pw[wq] &= (zb << 16) - zb;  // 0 / 0xFFFF / 0xFFFF0000 / 0xFFFFFFFF
      }
      bf16x8 pm = __builtin_bit_cast(bf16x8, pw);
      accS[rt] = __builtin_amdgcn_mfma_f32_16x16x32_bf16(pm, ones, accS[rt], 0, 0, 0);
#pragma unroll
      for (int dt = 0; dt < 2; ++dt)
        acc[rt][dt] =
            __builtin_amdgcn_mfma_f32_16x16x32_bf16(pm, vvb[jj][dt], acc[rt][dt], 0, 0, 0);
    }
  }
}

__global__ __launch_bounds__(256, 4) void k_attn(const __bf16* __restrict__ Qh,
                                                 const __bf16* __restrict__ Kh,
                                                 const __bf16* __restrict__ VT,
                                                 const u64* __restrict__ mbits,
                                                 __bf16* __restrict__ O) {
  __shared__ __bf16 Klds[2][2048];  // [64 rows][4 slots x 16B], slot-swizzled
  __shared__ __bf16 Vlds[2][2048];  // [32 d][8 granules x 16B], granule-swizzled
  const int tid = threadIdx.x;
  const int l = tid & 63, w = tid >> 6;
  const int g = l >> 4, q16 = l & 15;
  const int bid = blockIdx.x;
  const int bh = (bid & 7) * 4 + ((bid >> 3) & 3);  // XCD-aware decode
  const int qx = bid >> 5;                          // 0..31
  const int q0 = qx * 128 + w * 32;
  const __bf16* Qb = Qh + (size_t)bh * NSEQ * HDIM;
  const __bf16* Kb = Kh + (size_t)bh * NSEQ * HDIM;
  const __bf16* Vb = VT + (size_t)bh * HDIM * NSEQ;  // [32 d][4096 kp]
  const u64* mr0 = mbits + (size_t)(q0 + q16) * 64;
  const u64* mr1 = mbits + (size_t)(q0 + 16 + q16) * 64;

  // staging sources (pre-swizzled: linear LDS dest + swizzled read match)
  const int rk = tid >> 2, gsK = (tid & 3) ^ ((rk >> 1) & 3);
  const __bf16* srcK = Kb + (size_t)rk * HDIM + gsK * 8;   // += t*2048
  const int dv = tid >> 3, gv = (tid & 7) ^ (dv & 7);
  const __bf16* srcV = Vb + (size_t)dv * NSEQ + gv * 8;    // += t*64

  // LDS read offsets (loop-invariant, elements)
  const int kOff = q16 * 32 + (g ^ ((q16 >> 1) & 3)) * 8;
  int vOff[2][2];
#pragma unroll
  for (int jj = 0; jj < 2; ++jj)
#pragma unroll
    for (int dt = 0; dt < 2; ++dt) {
      int d = dt * 16 + q16;
      vOff[jj][dt] = d * 64 + ((4 * jj + g) ^ (d & 7)) * 8;
    }

  bf16x8 qf[2];
#pragma unroll
  for (int rt = 0; rt < 2; ++rt)
    qf[rt] = *reinterpret_cast<const bf16x8*>(
        Qb + (size_t)(q0 + rt * 16 + q16) * HDIM + g * 8);

  bf16x8 ones;
#pragma unroll
  for (int e = 0; e < 8; ++e) ones[e] = (__bf16)1.0f;

  f32x4 acc[2][2] = {};
  f32x4 accS[2] = {};

  // prologue: stage tile 0 into buf0, prefetch its mask words
  gload16(&Klds[0][0] + tid * 8, srcK);
  gload16(&Vlds[0][0] + tid * 8, srcV);
  u64 a0 = mr0[0], a1 = mr1[0];
  u64 b0, b1;
  __syncthreads();

  for (int t = 0; t < 64; t += 2) {
    // phase A: stage t+1 -> buf1, compute t from buf0
    gload16(&Klds[1][0] + tid * 8, srcK + (size_t)(t + 1) * 2048);
    gload16(&Vlds[1][0] + tid * 8, srcV + (size_t)(t + 1) * 64);
    b0 = mr0[t + 1]; b1 = mr1[t + 1];
    attn_compute(&Klds[0][0], &Vlds[0][0], qf, a0, a1, acc, accS, kOff, vOff, ones, g);
    __syncthreads();
    // phase B: stage t+2 -> buf0 (clamped), compute t+1 from buf1
    const int t2 = (t + 2 < 64) ? t + 2 : 63;
    gload16(&Klds[0][0] + tid * 8, srcK + (size_t)t2 * 2048);
    gload16(&Vlds[0][0] + tid * 8, srcV + (size_t)t2 * 64);
    a0 = mr0[t2]; a1 = mr1[t2];
    attn_compute(&Klds[1][0], &Vlds[1][0], qf, b0, b1, acc, accS, kOff, vOff, ones, g);
    __syncthreads();
  }

  const int bb = bh >> 4, hh = bh & 15;
#pragma unroll
  for (int rt = 0; rt < 2; ++rt)
#pragma unroll
    for (int r = 0; r < 4; ++r) {
      float inv = 1.f / accS[rt][r];  // denominator in same lane/reg as numerator
      int qrow = q0 + rt * 16 + g * 4 + r;
#pragma unroll
      for (int dt = 0; dt < 2; ++dt)
        O[((size_t)bb * NSEQ + qrow) * DIMQ + hh * HDIM + dt * 16 + q16] =
            (__bf16)(acc[rt][dt][r] * inv);
    }
}

// ---------------- output projection GEMM (fp32 output) ----------------
__global__ __launch_bounds__(256) void k_gemm_proj(const __bf16* __restrict__ A,
                                                   const __bf16* __restrict__ Bt,
                                                   float* __restrict__ Out) {
  __shared__ __bf16 As[128 * 64], Bs[128 * 64];
  f32x4 acc[4][4] = {};
  const int l = threadIdx.x & 63, w = threadIdx.x >> 6, wr = w >> 1, wc = w & 1;
  const int m0 = blockIdx.y * 128, n0 = blockIdx.x * 128;
  gemm_mainloop(A, Bt, m0, n0, As, Bs, acc);
#pragma unroll
  for (int nt = 0; nt < 4; ++nt) {
    int n = n0 + wc * 64 + nt * 16 + (l & 15);
#pragma unroll
    for (int mt = 0; mt < 4; ++mt) {
      int m = m0 + wr * 64 + mt * 16 + (l >> 4) * 4;
      f32x4 v = acc[mt][nt];
      float* p = Out + (size_t)m * DIMQ + n;
      p[0] = v[0]; p[DIMQ] = v[1];
      p[2 * DIMQ] = v[2]; p[3 * DIMQ] = v[3];
    }
  }
}

// ---------------- launcher ----------------
extern "C" void kernel_launch(void* const* d_in, const int* in_sizes, int n_in,
                              void* d_out, int out_size, void* d_ws, size_t ws_size,
                              hipStream_t stream) {
  (void)in_sizes; (void)n_in; (void)out_size; (void)ws_size;
  const float* batch  = (const float*)d_in[0];
  const float* w_qkv  = (const float*)d_in[1];
  const float* w_proj = (const float*)d_in[2];
  const int*   cmask  = (const int*)d_in[3];

  __bf16* Abf = (__bf16*)d_ws;                       // 8192*512 bf16
  __bf16* WqT = Abf + (size_t)8192 * 512;            // 1536*512
  __bf16* WpT = WqT + (size_t)1536 * 512;            // 512*512
  u64*    mb  = (u64*)(WpT + (size_t)512 * 512);     // 4096*64 u64
  __bf16* Qh  = (__bf16*)(mb + (size_t)4096 * 64);   // 32*4096*32
  __bf16* Kh  = Qh + (size_t)32 * NSEQ * HDIM;
  __bf16* VT  = Kh + (size_t)32 * NSEQ * HDIM;
  __bf16* Obf = VT + (size_t)32 * NSEQ * HDIM;       // 8192*512

  k_cvt_bf16<<<4096, 256, 0, stream>>>(batch, Abf);
  k_cvtT<<<dim3(24, 8), 256, 0, stream>>>(w_qkv, WqT, 1536);
  k_cvtT<<<dim3(8, 8), 256, 0, stream>>>(w_proj, WpT, 512);
  k_maskbits<<<4096, 256, 0, stream>>>(cmask, mb);
  k_gemm_qkv<<<dim3(12, 64), 256, 0, stream>>>(Abf, WqT, Qh, Kh, VT);
  k_attn<<<1024, 256, 0, stream>>>(Qh, Kh, VT, mb, Obf);
  k_gemm_proj<<<dim3(4, 64), 256, 0, stream>>>(Obf, WpT, (float*)d_out);
}

// Round 11
// 244.998 us; speedup vs baseline: 1.2035x; 1.0113x over previous
//
#include <hip/hip_runtime.h>
#include <hip/hip_bf16.h>

typedef __attribute__((ext_vector_type(4))) float f32x4;
typedef __attribute__((ext_vector_type(8))) __bf16 bf16x8;
typedef __attribute__((ext_vector_type(4))) __bf16 bf16x4;
typedef __attribute__((ext_vector_type(4))) unsigned int u32x4;
typedef unsigned long long u64;
typedef unsigned int u32;

#define DIMQ 512
#define NSEQ 4096
#define NHEAD 16
#define HDIM 32
#define SCALE_QK 0.17677669529663687f
#define C2F (SCALE_QK * 1.4426950408889634f)  // scale * log2(e), folded into Q

__device__ __forceinline__ void gload16(void* lds, const void* g) {
  __builtin_amdgcn_global_load_lds(
      (const __attribute__((address_space(1))) void*)g,
      (__attribute__((address_space(3))) void*)lds, 16, 0, 0);
}

// ---------------- conversion kernels ----------------

__global__ __launch_bounds__(256) void k_cvt_bf16(const float* __restrict__ in,
                                                  __bf16* __restrict__ out) {
  int i = blockIdx.x * 256 + threadIdx.x;
  float4 v = reinterpret_cast<const float4*>(in)[i];
  bf16x4 o;
  o.x = (__bf16)v.x; o.y = (__bf16)v.y; o.z = (__bf16)v.z; o.w = (__bf16)v.w;
  reinterpret_cast<bf16x4*>(out)[i] = o;
}

// in: fp32 [512][Nc]  ->  out: bf16 [Nc][512]  (transpose via LDS tile)
__global__ __launch_bounds__(256) void k_cvtT(const float* __restrict__ in,
                                              __bf16* __restrict__ out, int Nc) {
  __shared__ __bf16 t[64][72];
  int k0 = blockIdx.y * 64, n0 = blockIdx.x * 64;
  int c = threadIdx.x & 63, rr = threadIdx.x >> 6;
#pragma unroll
  for (int i = 0; i < 16; ++i) {
    int r = rr * 16 + i;
    t[r][c] = (__bf16)in[(size_t)(k0 + r) * Nc + n0 + c];
  }
  __syncthreads();
#pragma unroll
  for (int i = 0; i < 16; ++i) {
    int r = rr * 16 + i;
    out[(size_t)(n0 + r) * 512 + k0 + c] = t[c][r];
  }
}

// int32 mask [4096][4096] -> PERMUTED bit mask [4096][64] u64.
// Lane l ballots column kvp(l) so the two mask bits of each packed-bf16 pair
// (pa elements 2w,2w+1) sit 16 bits apart:
//   mt bit l  <->  kv = 32*l5 | 16*l1 | (l3:2)*4 | 2*l0 | l4
__global__ __launch_bounds__(256) void k_maskbits(const int* __restrict__ mask,
                                                  u64* __restrict__ bits) {
  int row = blockIdx.x;
  int l = threadIdx.x & 63, w = threadIdx.x >> 6;
  const int jj = l >> 5, odd = (l >> 4) & 1, gg = (l >> 2) & 3, wb = l & 3;
  const int kvp = 32 * jj + 16 * (wb >> 1) + 4 * gg + 2 * (wb & 1) + odd;
  const int* mr = mask + (size_t)row * NSEQ;
  for (int t = w; t < 64; t += 4) {
    u64 b = __ballot(mr[t * 64 + kvp] != 0);
    if (l == 0) bits[(size_t)row * 64 + t] = b;
  }
}

// ---------------- shared GEMM main loop (m97-style, swizzled gload_lds) ----------------
__device__ __forceinline__ void gemm_mainloop(const __bf16* __restrict__ A,
                                              const __bf16* __restrict__ Bt,
                                              int m0, int n0,
                                              __bf16* As, __bf16* Bs,
                                              f32x4 acc[4][4]) {
  const int tid = threadIdx.x, l = tid & 63, w = tid >> 6;
  const int wr = w >> 1, wc = w & 1;
  for (int kt = 0; kt < DIMQ; kt += 64) {
    __syncthreads();
#pragma unroll
    for (int it = 0; it < 4; ++it) {
      int c = it * 256 + tid;
      int row = c >> 3, j = c & 7, js = j ^ (row & 7);
      gload16(As + (size_t)(it * 256 + w * 64) * 8,
              A + (size_t)(m0 + row) * DIMQ + kt + js * 8);
      gload16(Bs + (size_t)(it * 256 + w * 64) * 8,
              Bt + (size_t)(n0 + row) * DIMQ + kt + js * 8);
    }
    __syncthreads();
#pragma unroll
    for (int kk = 0; kk < 2; ++kk) {
      bf16x8 a[4], b[4];
#pragma unroll
      for (int mt = 0; mt < 4; ++mt) {
        int row = wr * 64 + mt * 16 + (l & 15);
        int g = (kk * 4 + (l >> 4)) ^ (row & 7);
        a[mt] = *reinterpret_cast<const bf16x8*>((const char*)As + row * 128 + g * 16);
      }
#pragma unroll
      for (int nt = 0; nt < 4; ++nt) {
        int row = wc * 64 + nt * 16 + (l & 15);
        int g = (kk * 4 + (l >> 4)) ^ (row & 7);
        b[nt] = *reinterpret_cast<const bf16x8*>((const char*)Bs + row * 128 + g * 16);
      }
#pragma unroll
      for (int mt = 0; mt < 4; ++mt)
#pragma unroll
        for (int nt = 0; nt < 4; ++nt)
          acc[mt][nt] = __builtin_amdgcn_mfma_f32_16x16x32_bf16(a[mt], b[nt], acc[mt][nt], 0, 0, 0);
    }
  }
}

// ---------------- QKV GEMM (epilogue: head layout; Q pre-scaled; V transposed + k-permuted) ----------------
__global__ __launch_bounds__(256) void k_gemm_qkv(const __bf16* __restrict__ A,
                                                  const __bf16* __restrict__ Bt,
                                                  __bf16* __restrict__ Qh,
                                                  __bf16* __restrict__ Kh,
                                                  __bf16* __restrict__ VT) {
  __shared__ __bf16 As[128 * 64], Bs[128 * 64];
  f32x4 acc[4][4] = {};
  const int l = threadIdx.x & 63, w = threadIdx.x >> 6, wr = w >> 1, wc = w & 1;
  const int m0 = blockIdx.y * 128, n0 = blockIdx.x * 128;
  gemm_mainloop(A, Bt, m0, n0, As, Bs, acc);
#pragma unroll
  for (int nt = 0; nt < 4; ++nt) {
    int n = n0 + wc * 64 + nt * 16 + (l & 15);
    int sec = n >> 9;           // 0=q 1=k 2=v
    int hh = (n >> 5) & 15;     // head
    int d = n & 31;             // dim in head
#pragma unroll
    for (int mt = 0; mt < 4; ++mt) {
      int m = m0 + wr * 64 + mt * 16 + (l >> 4) * 4;
      int bb = m >> 12, nn = m & 4095;
      size_t bh = (size_t)bb * NHEAD + hh;
      f32x4 v = acc[mt][nt];
      if (sec == 0) {
        __bf16* p = Qh + (bh * NSEQ + nn) * HDIM + d;
        p[0] = (__bf16)(v[0] * C2F); p[HDIM] = (__bf16)(v[1] * C2F);
        p[2 * HDIM] = (__bf16)(v[2] * C2F); p[3 * HDIM] = (__bf16)(v[3] * C2F);
      } else if (sec == 1) {
        __bf16* p = Kh + (bh * NSEQ + nn) * HDIM + d;
        p[0] = (__bf16)v[0]; p[HDIM] = (__bf16)v[1];
        p[2 * HDIM] = (__bf16)v[2]; p[3 * HDIM] = (__bf16)v[3];
      } else {
        // k-permuted V: within each 32-kv group, low5 = hi*16 + g*4 + r -> g*8 + hi*4 + r
        // (nn % 4 == 0, so r = 0 for the vector base)
        int low = nn & 31;
        int nnp = (nn & ~31) | (((low >> 2) & 3) << 3) | (((low >> 4) & 1) << 2);
        bf16x4 o;
        o.x = (__bf16)v[0]; o.y = (__bf16)v[1]; o.z = (__bf16)v[2]; o.w = (__bf16)v[3];
        *reinterpret_cast<bf16x4*>(VT + (bh * HDIM + d) * NSEQ + nnp) = o;
      }
    }
  }
}

// ---------------- fused masked attention, v8 ----------------
// As v7 (grid 1024 XCD-decoded, 4 waves x 32 q-rows, packed-AND mask, MFMA
// row-sums) but the K/V pipeline is a 4-slot LDS ring with stage-2-ahead,
// counted s_waitcnt vmcnt(8) + RAW s_barrier (no vmcnt(0) drain): prefetched
// loads stay in flight across barriers (T3/T4). Issue order pinned with
// sched_barrier(0); each phase issues exactly 4 VMEM (2 gload_lds + 2 mask).
__device__ __forceinline__ void attn_compute(const __bf16* __restrict__ Kl,
                                             const __bf16* __restrict__ Vl,
                                             const bf16x8 qf[2], u64 mw0, u64 mw1,
                                             f32x4 acc[2][2], f32x4 accS[2],
                                             int kOff, const int vOff[2][2],
                                             bf16x8 ones, int g) {
  bf16x8 kf[4];
#pragma unroll
  for (int f = 0; f < 4; ++f)
    kf[f] = *reinterpret_cast<const bf16x8*>(Kl + kOff + f * 512);

  bf16x8 vvb[2][2];  // [jj][dt], single b128 each
#pragma unroll
  for (int jj = 0; jj < 2; ++jj)
#pragma unroll
    for (int dt = 0; dt < 2; ++dt)
      vvb[jj][dt] = *reinterpret_cast<const bf16x8*>(Vl + vOff[jj][dt]);

  const f32x4 z4 = {0.f, 0.f, 0.f, 0.f};
#pragma unroll
  for (int rt = 0; rt < 2; ++rt) {
    const u64 mw = rt ? mw1 : mw0;
#pragma unroll
    for (int jj = 0; jj < 2; ++jj) {
      // S^T for kv halves f=2jj, 2jj+1: lane holds q=q16, k=16f+4g+r
      f32x4 s0 = __builtin_amdgcn_mfma_f32_16x16x32_bf16(kf[2 * jj], qf[rt], z4, 0, 0, 0);
      f32x4 s1 = __builtin_amdgcn_mfma_f32_16x16x32_bf16(kf[2 * jj + 1], qf[rt], z4, 0, 0, 0);
      bf16x8 pa;  // k order e = hi*4 + r matches permuted-V b128 order
#pragma unroll
      for (int r = 0; r < 4; ++r) {
        pa[r] = (__bf16)__builtin_exp2f(s0[r]);
        pa[r + 4] = (__bf16)__builtin_exp2f(s1[r]);
      }
      const u32 x = ((u32)(mw >> (32 * jj))) >> (g * 4);
      u32x4 pw = __builtin_bit_cast(u32x4, pa);
#pragma unroll
      for (int wq = 0; wq < 4; ++wq) {
        u32 zb = (x >> wq) & 0x10001u;
        pw[wq] &= (zb << 16) - zb;  // 0 / 0xFFFF / 0xFFFF0000 / 0xFFFFFFFF
      }
      bf16x8 pm = __builtin_bit_cast(bf16x8, pw);
      accS[rt] = __builtin_amdgcn_mfma_f32_16x16x32_bf16(pm, ones, accS[rt], 0, 0, 0);
#pragma unroll
      for (int dt = 0; dt < 2; ++dt)
        acc[rt][dt] =
            __builtin_amdgcn_mfma_f32_16x16x32_bf16(pm, vvb[jj][dt], acc[rt][dt], 0, 0, 0);
    }
  }
}

// One pipeline phase: stage tile T+2 into slot SN, wait counted vmcnt, raw
// barrier, compute tile T from slot SC. Exactly 4 VMEM issued per phase, in a
// sched_barrier-pinned group, so vmcnt(8) == "all but the newest 2 phases".
#define ATTN_PHASE(T, KC, VC, KN, VN, MAC, MBC, MAN, MBN)                     \
  {                                                                           \
    int ts_ = (T) + 2; if (ts_ > 63) ts_ = 63;                                \
    __builtin_amdgcn_sched_barrier(0);                                        \
    gload16(&(KN)[0] + tid * 8, srcK + (size_t)ts_ * 2048);                   \
    gload16(&(VN)[0] + tid * 8, srcV + (size_t)ts_ * 64);                     \
    MAN = mr0[ts_];                                                           \
    MBN = mr1[ts_];                                                           \
    __builtin_amdgcn_sched_barrier(0);                                        \
    asm volatile("s_waitcnt vmcnt(8)" ::: "memory");                          \
    __builtin_amdgcn_sched_barrier(0);                                        \
    __builtin_amdgcn_s_barrier();                                             \
    __builtin_amdgcn_sched_barrier(0);                                        \
    attn_compute(&(KC)[0], &(VC)[0], qf, MAC, MBC, acc, accS, kOff, vOff,     \
                 ones, g);                                                    \
  }

__global__ __launch_bounds__(256, 4) void k_attn(const __bf16* __restrict__ Qh,
                                                 const __bf16* __restrict__ Kh,
                                                 const __bf16* __restrict__ VT,
                                                 const u64* __restrict__ mbits,
                                                 __bf16* __restrict__ O) {
  __shared__ __bf16 K0[2048], K1[2048], K2[2048], K3[2048];  // 4-slot K ring
  __shared__ __bf16 V0[2048], V1[2048], V2[2048], V3[2048];  // 4-slot V ring
  const int tid = threadIdx.x;
  const int l = tid & 63, w = tid >> 6;
  const int g = l >> 4, q16 = l & 15;
  const int bid = blockIdx.x;
  const int bh = (bid & 7) * 4 + ((bid >> 3) & 3);  // XCD-aware decode
  const int qx = bid >> 5;                          // 0..31
  const int q0 = qx * 128 + w * 32;
  const __bf16* Qb = Qh + (size_t)bh * NSEQ * HDIM;
  const __bf16* Kb = Kh + (size_t)bh * NSEQ * HDIM;
  const __bf16* Vb = VT + (size_t)bh * HDIM * NSEQ;  // [32 d][4096 kp]
  const u64* mr0 = mbits + (size_t)(q0 + q16) * 64;
  const u64* mr1 = mbits + (size_t)(q0 + 16 + q16) * 64;

  // staging sources (pre-swizzled: linear LDS dest + swizzled read match)
  const int rk = tid >> 2, gsK = (tid & 3) ^ ((rk >> 1) & 3);
  const __bf16* srcK = Kb + (size_t)rk * HDIM + gsK * 8;   // += t*2048
  const int dv = tid >> 3, gv = (tid & 7) ^ (dv & 7);
  const __bf16* srcV = Vb + (size_t)dv * NSEQ + gv * 8;    // += t*64

  // LDS read offsets (loop-invariant, elements)
  const int kOff = q16 * 32 + (g ^ ((q16 >> 1) & 3)) * 8;
  int vOff[2][2];
#pragma unroll
  for (int jj = 0; jj < 2; ++jj)
#pragma unroll
    for (int dt = 0; dt < 2; ++dt) {
      int d = dt * 16 + q16;
      vOff[jj][dt] = d * 64 + ((4 * jj + g) ^ (d & 7)) * 8;
    }

  bf16x8 qf[2];
#pragma unroll
  for (int rt = 0; rt < 2; ++rt)
    qf[rt] = *reinterpret_cast<const bf16x8*>(
        Qb + (size_t)(q0 + rt * 16 + q16) * HDIM + g * 8);

  bf16x8 ones;
#pragma unroll
  for (int e = 0; e < 8; ++e) ones[e] = (__bf16)1.0f;

  f32x4 acc[2][2] = {};
  f32x4 accS[2] = {};

  u64 mA0, mA1, mA2, mA3, mB0, mB1, mB2, mB3;

  // prologue: stage tiles 0 and 1 (two pinned groups of 4 VMEM each)
  __builtin_amdgcn_sched_barrier(0);
  gload16(&K0[0] + tid * 8, srcK);
  gload16(&V0[0] + tid * 8, srcV);
  mA0 = mr0[0]; mB0 = mr1[0];
  __builtin_amdgcn_sched_barrier(0);
  gload16(&K1[0] + tid * 8, srcK + 2048);
  gload16(&V1[0] + tid * 8, srcV + 64);
  mA1 = mr0[1]; mB1 = mr1[1];
  __builtin_amdgcn_sched_barrier(0);

  for (int tb = 0; tb < 64; tb += 4) {
    ATTN_PHASE(tb + 0, K0, V0, K2, V2, mA0, mB0, mA2, mB2);
    ATTN_PHASE(tb + 1, K1, V1, K3, V3, mA1, mB1, mA3, mB3);
    ATTN_PHASE(tb + 2, K2, V2, K0, V0, mA2, mB2, mA0, mB0);
    ATTN_PHASE(tb + 3, K3, V3, K1, V1, mA3, mB3, mA1, mB1);
  }

  const int bb = bh >> 4, hh = bh & 15;
#pragma unroll
  for (int rt = 0; rt < 2; ++rt)
#pragma unroll
    for (int r = 0; r < 4; ++r) {
      float inv = 1.f / accS[rt][r];  // denominator in same lane/reg as numerator
      int qrow = q0 + rt * 16 + g * 4 + r;
#pragma unroll
      for (int dt = 0; dt < 2; ++dt)
        O[((size_t)bb * NSEQ + qrow) * DIMQ + hh * HDIM + dt * 16 + q16] =
            (__bf16)(acc[rt][dt][r] * inv);
    }
}

// ---------------- output projection GEMM (fp32 output) ----------------
__global__ __launch_bounds__(256) void k_gemm_proj(const __bf16* __restrict__ A,
                                                   const __bf16* __restrict__ Bt,
                                                   float* __restrict__ Out) {
  __shared__ __bf16 As[128 * 64], Bs[128 * 64];
  f32x4 acc[4][4] = {};
  const int l = threadIdx.x & 63, w = threadIdx.x >> 6, wr = w >> 1, wc = w & 1;
  const int m0 = blockIdx.y * 128, n0 = blockIdx.x * 128;
  gemm_mainloop(A, Bt, m0, n0, As, Bs, acc);
#pragma unroll
  for (int nt = 0; nt < 4; ++nt) {
    int n = n0 + wc * 64 + nt * 16 + (l & 15);
#pragma unroll
    for (int mt = 0; mt < 4; ++mt) {
      int m = m0 + wr * 64 + mt * 16 + (l >> 4) * 4;
      f32x4 v = acc[mt][nt];
      float* p = Out + (size_t)m * DIMQ + n;
      p[0] = v[0]; p[DIMQ] = v[1];
      p[2 * DIMQ] = v[2]; p[3 * DIMQ] = v[3];
    }
  }
}

// ---------------- launcher ----------------
extern "C" void kernel_launch(void* const* d_in, const int* in_sizes, int n_in,
                              void* d_out, int out_size, void* d_ws, size_t ws_size,
                              hipStream_t stream) {
  (void)in_sizes; (void)n_in; (void)out_size; (void)ws_size;
  const float* batch  = (const float*)d_in[0];
  const float* w_qkv  = (const float*)d_in[1];
  const float* w_proj = (const float*)d_in[2];
  const int*   cmask  = (const int*)d_in[3];

  __bf16* Abf = (__bf16*)d_ws;                       // 8192*512 bf16
  __bf16* WqT = Abf + (size_t)8192 * 512;            // 1536*512
  __bf16* WpT = WqT + (size_t)1536 * 512;            // 512*512
  u64*    mb  = (u64*)(WpT + (size_t)512 * 512);     // 4096*64 u64
  __bf16* Qh  = (__bf16*)(mb + (size_t)4096 * 64);   // 32*4096*32
  __bf16* Kh  = Qh + (size_t)32 * NSEQ * HDIM;
  __bf16* VT  = Kh + (size_t)32 * NSEQ * HDIM;
  __bf16* Obf = VT + (size_t)32 * NSEQ * HDIM;       // 8192*512

  k_cvt_bf16<<<4096, 256, 0, stream>>>(batch, Abf);
  k_cvtT<<<dim3(24, 8), 256, 0, stream>>>(w_qkv, WqT, 1536);
  k_cvtT<<<dim3(8, 8), 256, 0, stream>>>(w_proj, WpT, 512);
  k_maskbits<<<4096, 256, 0, stream>>>(cmask, mb);
  k_gemm_qkv<<<dim3(12, 64), 256, 0, stream>>>(Abf, WqT, Qh, Kh, VT);
  k_attn<<<1024, 256, 0, stream>>>(Qh, Kh, VT, mb, Obf);
  k_gemm_proj<<<dim3(4, 64), 256, 0, stream>>>(Obf, WpT, (float*)d_out);
}